// Round 2
// baseline (713.182 us; speedup 1.0000x reference)
//
#include <hip/hip_runtime.h>
#include <hip/hip_bf16.h>
#include <stdint.h>

#define NB 64
#define NV 2048
#define NL 512
#define DK 512
#define BT 128
#define BK 64
#define LDP 72   // padded LDS row stride in bf16 elems (144 B = 36 banks -> 2-way max, free)

typedef __attribute__((ext_vector_type(8))) short bf16x8;
typedef __attribute__((ext_vector_type(4))) float f32x4;

// order-preserving float -> uint map (for atomicMin); all-ones = +infinity sentinel
__device__ __forceinline__ unsigned enc_f(float f) {
  unsigned u = __float_as_uint(f);
  return (u & 0x80000000u) ? ~u : (u | 0x80000000u);
}
__device__ __forceinline__ float dec_f(unsigned u) {
  unsigned b = (u & 0x80000000u) ? (u ^ 0x80000000u) : ~u;
  return __uint_as_float(b);
}

// fp32 -> bf16 (RNE), two packed into one uint. Inputs are finite (no NaN path).
__device__ __forceinline__ unsigned short f2bf(float f) {
  unsigned u = __float_as_uint(f);
  u += 0x7FFFu + ((u >> 16) & 1u);
  return (unsigned short)(u >> 16);
}
__device__ __forceinline__ unsigned pack_bf2(float lo, float hi) {
  return (unsigned)f2bf(lo) | ((unsigned)f2bf(hi) << 16);
}

// Fused (video . lang^T) GEMM + chamfer min-reductions.
// grid: 64 batches * 16 v-tiles * 4 l-tiles; block 256 = 4 waves, each 64x64 out.
__global__ __launch_bounds__(256, 2) void chamfer_main(
    const float* __restrict__ video, const float* __restrict__ lang,
    unsigned* __restrict__ rowmin, unsigned* __restrict__ colmin) {
  __shared__ unsigned short Asm[BT][LDP];
  __shared__ unsigned short Bsm[BT][LDP];
  __shared__ float rn_s[BT];
  __shared__ float cn_s[BT];

  const int bid = blockIdx.x;
  const int b  = bid >> 6;          // batch
  const int vt = (bid >> 2) & 15;   // video tile (lt fastest -> A-tile L2 reuse)
  const int lt = bid & 3;           // lang tile

  const float* Ag = video + ((size_t)b * NV + (size_t)vt * BT) * DK;
  const float* Bg = lang  + ((size_t)b * NL + (size_t)lt * BT) * DK;

  const int t = threadIdx.x;
  const int lane = t & 63;
  const int w = t >> 6;
  const int wrow = (w >> 1) * 64;
  const int wcol = (w & 1) * 64;

  // staging map: thread t covers rows (t>>4)+16i, k-chunk (t&15)*4 (float4 granularity)
  const int sg = t >> 4;
  const int sk = (t & 15) * 4;

  float rnA[8], rnB[8];                       // exact fp32 norm partials
  #pragma unroll
  for (int i = 0; i < 8; i++) { rnA[i] = 0.f; rnB[i] = 0.f; }

  f32x4 acc[4][4];
  #pragma unroll
  for (int i = 0; i < 4; i++)
    #pragma unroll
    for (int j = 0; j < 4; j++)
      acc[i][j] = (f32x4){0.f, 0.f, 0.f, 0.f};

  for (int k0 = 0; k0 < DK; k0 += BK) {
    __syncthreads();  // LDS reuse guard
    #pragma unroll
    for (int i = 0; i < 8; i++) {
      const int r = sg + 16 * i;
      const float4 va = *(const float4*)(Ag + (size_t)r * DK + k0 + sk);
      const float4 vb = *(const float4*)(Bg + (size_t)r * DK + k0 + sk);
      rnA[i] += va.x * va.x + va.y * va.y + va.z * va.z + va.w * va.w;
      rnB[i] += vb.x * vb.x + vb.y * vb.y + vb.z * vb.z + vb.w * vb.w;
      uint2 pa, pb;
      pa.x = pack_bf2(va.x, va.y);
      pa.y = pack_bf2(va.z, va.w);
      pb.x = pack_bf2(vb.x, vb.y);
      pb.y = pack_bf2(vb.z, vb.w);
      *(uint2*)&Asm[r][sk] = pa;
      *(uint2*)&Bsm[r][sk] = pb;
    }
    __syncthreads();
    #pragma unroll
    for (int ks = 0; ks < 2; ks++) {
      const int kb = ks * 32 + (lane >> 4) * 8;
      bf16x8 af[4], bfr[4];
      #pragma unroll
      for (int i = 0; i < 4; i++)
        af[i] = *(const bf16x8*)&Asm[wrow + i * 16 + (lane & 15)][kb];
      #pragma unroll
      for (int j = 0; j < 4; j++)
        bfr[j] = *(const bf16x8*)&Bsm[wcol + j * 16 + (lane & 15)][kb];
      #pragma unroll
      for (int i = 0; i < 4; i++)
        #pragma unroll
        for (int j = 0; j < 4; j++)
          acc[i][j] = __builtin_amdgcn_mfma_f32_16x16x32_bf16(af[i], bfr[j], acc[i][j], 0, 0, 0);
    }
  }

  // combine norm partials: rows R=(t>>4)+16i, summed across the 16 lanes (t&15)
  #pragma unroll
  for (int i = 0; i < 8; i++) {
    float a = rnA[i], bb = rnB[i];
    #pragma unroll
    for (int m = 1; m < 16; m <<= 1) {
      a  += __shfl_xor(a, m, 64);
      bb += __shfl_xor(bb, m, 64);
    }
    rnA[i] = a; rnB[i] = bb;
  }
  if ((t & 15) == 0) {
    #pragma unroll
    for (int i = 0; i < 8; i++) {
      rn_s[sg + 16 * i] = rnA[i];
      cn_s[sg + 16 * i] = rnB[i];
    }
  }
  __syncthreads();

  // epilogue: P = rn + cn - 2*dot; C layout col=lane&15, row=(lane>>4)*4+reg
  const int g = lane >> 4;
  const int c = lane & 15;
  float cn[4];
  #pragma unroll
  for (int j = 0; j < 4; j++) cn[j] = cn_s[wcol + j * 16 + c];

  const size_t rowbase = (size_t)b * NV + (size_t)vt * BT + wrow;
  const size_t colbase = (size_t)b * NL + (size_t)lt * BT + wcol;

  float cmin[4];
  #pragma unroll
  for (int j = 0; j < 4; j++) cmin[j] = 3.0e38f;

  #pragma unroll
  for (int i = 0; i < 4; i++) {
    #pragma unroll
    for (int r = 0; r < 4; r++) {
      const float rn = rn_s[wrow + i * 16 + g * 4 + r];
      float m = 3.0e38f;
      #pragma unroll
      for (int j = 0; j < 4; j++) {
        const float P = rn + cn[j] - 2.0f * acc[i][j][r];
        m = fminf(m, P);
        cmin[j] = fminf(cmin[j], P);
      }
      #pragma unroll
      for (int mm = 1; mm < 16; mm <<= 1)
        m = fminf(m, __shfl_xor(m, mm, 64));   // min across the 16 cols held per lane group
      if (c == 0)
        atomicMin(&rowmin[rowbase + i * 16 + g * 4 + r], enc_f(m));
    }
  }
  #pragma unroll
  for (int j = 0; j < 4; j++) {
    float m = cmin[j];
    m = fminf(m, __shfl_xor(m, 16, 64));       // min across the 4 row groups
    m = fminf(m, __shfl_xor(m, 32, 64));
    if (g == 0)
      atomicMin(&colmin[colbase + j * 16 + c], enc_f(m));
  }
}

__global__ void chamfer_reduce(const unsigned* __restrict__ rowmin,
                               const unsigned* __restrict__ colmin,
                               float* __restrict__ out) {
  const int b = blockIdx.x;
  const int t = threadIdx.x;
  float s = 0.f;
  for (int i = t; i < NV; i += 256) s += dec_f(rowmin[(size_t)b * NV + i]) * (1.0f / NV);
  for (int i = t; i < NL; i += 256) s += dec_f(colmin[(size_t)b * NL + i]) * (1.0f / NL);
  #pragma unroll
  for (int m = 1; m < 64; m <<= 1) s += __shfl_xor(s, m, 64);
  __shared__ float ws[4];
  if ((t & 63) == 0) ws[t >> 6] = s;
  __syncthreads();
  if (t == 0) out[b] = ws[0] + ws[1] + ws[2] + ws[3];
}

extern "C" void kernel_launch(void* const* d_in, const int* in_sizes, int n_in,
                              void* d_out, int out_size, void* d_ws, size_t ws_size,
                              hipStream_t stream) {
  const float* video = (const float*)d_in[0];
  const float* lang  = (const float*)d_in[1];
  float* out = (float*)d_out;
  unsigned* rowmin = (unsigned*)d_ws;
  unsigned* colmin = rowmin + (size_t)NB * NV;
  // init mins to +inf sentinel (0xFFFFFFFF); ws is re-poisoned before every launch
  (void)hipMemsetAsync(d_ws, 0xFF, (size_t)(NB * NV + NB * NL) * sizeof(unsigned), stream);
  chamfer_main<<<dim3(NB * 16 * 4), dim3(256), 0, stream>>>(video, lang, rowmin, colmin);
  chamfer_reduce<<<dim3(NB), dim3(256), 0, stream>>>(rowmin, colmin, out);
}

// Round 3
// 523.823 us; speedup vs baseline: 1.3615x; 1.3615x over previous
//
#include <hip/hip_runtime.h>
#include <hip/hip_bf16.h>
#include <stdint.h>

#define NB 64
#define NV 2048
#define NL 512
#define DK 512
#define BT 128
#define BK 64

typedef __attribute__((ext_vector_type(8))) short bf16x8;
typedef __attribute__((ext_vector_type(4))) float f32x4;

// order-preserving float -> uint map (for atomicMin); all-ones = +infinity sentinel
__device__ __forceinline__ unsigned enc_f(float f) {
  unsigned u = __float_as_uint(f);
  return (u & 0x80000000u) ? ~u : (u | 0x80000000u);
}
__device__ __forceinline__ float dec_f(unsigned u) {
  unsigned b = (u & 0x80000000u) ? (u ^ 0x80000000u) : ~u;
  return __uint_as_float(b);
}

// fp32 -> bf16 (RNE); inputs finite, no NaN path
__device__ __forceinline__ unsigned short f2bf(float f) {
  unsigned u = __float_as_uint(f);
  u += 0x7FFFu + ((u >> 16) & 1u);
  return (unsigned short)(u >> 16);
}
__device__ __forceinline__ unsigned pack_bf2(float lo, float hi) {
  return (unsigned)f2bf(lo) | ((unsigned)f2bf(hi) << 16);
}

// async global->LDS, 16 B per lane; LDS dest = wave-uniform base + lane*16
__device__ __forceinline__ void gload_lds16(const void* g, void* l) {
  __builtin_amdgcn_global_load_lds(
      (const __attribute__((address_space(1))) unsigned*)g,
      (__attribute__((address_space(3))) unsigned*)l, 16, 0, 0);
}

// ---------------- Pass 1: fp32 -> bf16 + exact fp32 row norms ----------------
// one wave per row of 512; grid = (NB*NV + NB*NL)/4 blocks of 256
__global__ __launch_bounds__(256) void convert_norm(
    const float* __restrict__ video, const float* __restrict__ lang,
    unsigned short* __restrict__ Vb, unsigned short* __restrict__ Lb,
    float* __restrict__ vnorm, float* __restrict__ lnorm) {
  const int t = threadIdx.x;
  const int lane = t & 63;
  const int row = blockIdx.x * 4 + (t >> 6);
  const int rows_v = NB * NV;

  const float* src;
  unsigned short* dst;
  float* nrm;
  size_t r;
  if (row < rows_v) { src = video; dst = Vb; nrm = vnorm; r = (size_t)row; }
  else              { src = lang;  dst = Lb;  nrm = lnorm; r = (size_t)(row - rows_v); }

  const float* p = src + r * DK;
  const float4 a = *(const float4*)(p + lane * 4);
  const float4 b = *(const float4*)(p + 256 + lane * 4);

  float n = a.x * a.x + a.y * a.y + a.z * a.z + a.w * a.w
          + b.x * b.x + b.y * b.y + b.z * b.z + b.w * b.w;
  #pragma unroll
  for (int m = 1; m < 64; m <<= 1) n += __shfl_xor(n, m, 64);

  uint2 pa, pb;
  pa.x = pack_bf2(a.x, a.y); pa.y = pack_bf2(a.z, a.w);
  pb.x = pack_bf2(b.x, b.y); pb.y = pack_bf2(b.z, b.w);
  *(uint2*)(dst + r * DK + lane * 4) = pa;
  *(uint2*)(dst + r * DK + 256 + lane * 4) = pb;
  if (lane == 0) nrm[r] = n;
}

// ---------------- Pass 2: bf16 GEMM + chamfer mins ----------------
// grid: 64 batches * 16 v-tiles * 4 l-tiles; block 256 = 4 waves, each 64x64 out.
// LDS [128][64] bf16 unpadded (global_load_lds needs linear lane order);
// XOR chunk swizzle: 16B chunk c of row r stored at slot c ^ (r&7)  -> 2-way max on reads.
__global__ __launch_bounds__(256, 4) void chamfer_gemm(
    const unsigned short* __restrict__ Vb, const unsigned short* __restrict__ Lb,
    const float* __restrict__ vnorm, const float* __restrict__ lnorm,
    unsigned* __restrict__ rowmin, unsigned* __restrict__ colmin) {
  __shared__ unsigned short Asm[BT][BK];
  __shared__ unsigned short Bsm[BT][BK];

  const int bid = blockIdx.x;
  const int b  = bid >> 6;
  const int vt = (bid >> 2) & 15;
  const int lt = bid & 3;

  const unsigned short* Ag = Vb + ((size_t)b * NV + (size_t)vt * BT) * DK;
  const unsigned short* Bg = Lb + ((size_t)b * NL + (size_t)lt * BT) * DK;

  const int t = threadIdx.x;
  const int lane = t & 63;
  const int w = t >> 6;
  const int wrow = (w >> 1) * 64;
  const int wcol = (w & 1) * 64;

  // staging: each wave stages 32 rows of A and 32 rows of B (4 instrs each, 8 rows/instr)
  const int lr = lane >> 3;        // row within 8-row group
  const int lp = lane & 7;         // dest slot within row
  const int schunk = lp ^ lr;      // source chunk (XOR swizzle)

  f32x4 acc[4][4];
  #pragma unroll
  for (int i = 0; i < 4; i++)
    #pragma unroll
    for (int j = 0; j < 4; j++)
      acc[i][j] = (f32x4){0.f, 0.f, 0.f, 0.f};

  const int c16 = lane & 15;
  const int hi  = lane >> 4;       // 0..3
  const int sw  = c16 & 7;         // read-side swizzle key (row&7)

  for (int k0 = 0; k0 < DK; k0 += BK) {
    __syncthreads();               // all waves done reading previous tile
    #pragma unroll
    for (int s = 0; s < 4; s++) {
      const int row = w * 32 + s * 8 + lr;
      gload_lds16(Ag + (size_t)row * DK + k0 + schunk * 8, &Asm[w * 32 + s * 8][0]);
      gload_lds16(Bg + (size_t)row * DK + k0 + schunk * 8, &Bsm[w * 32 + s * 8][0]);
    }
    __syncthreads();               // vmcnt(0) drain -> tile visible
    #pragma unroll
    for (int ks = 0; ks < 2; ks++) {
      const int ck = ks * 4 + hi;  // logical 16B chunk index in row
      bf16x8 af[4], bfr[4];
      #pragma unroll
      for (int i = 0; i < 4; i++)
        af[i] = *(const bf16x8*)&Asm[wrow + i * 16 + c16][(ck ^ sw) * 8];
      #pragma unroll
      for (int j = 0; j < 4; j++)
        bfr[j] = *(const bf16x8*)&Bsm[wcol + j * 16 + c16][(ck ^ sw) * 8];
      #pragma unroll
      for (int i = 0; i < 4; i++)
        #pragma unroll
        for (int j = 0; j < 4; j++)
          acc[i][j] = __builtin_amdgcn_mfma_f32_16x16x32_bf16(af[i], bfr[j], acc[i][j], 0, 0, 0);
    }
  }

  // epilogue: P = rn + cn - 2*dot; C layout col=lane&15, row=(lane>>4)*4+reg
  const int g = hi;
  const int c = c16;
  const size_t rowbase = (size_t)b * NV + (size_t)vt * BT + wrow;
  const size_t colbase = (size_t)b * NL + (size_t)lt * BT + wcol;

  float cn[4];
  #pragma unroll
  for (int j = 0; j < 4; j++) cn[j] = lnorm[colbase + j * 16 + c];

  float cmin[4];
  #pragma unroll
  for (int j = 0; j < 4; j++) cmin[j] = 3.0e38f;

  #pragma unroll
  for (int i = 0; i < 4; i++) {
    #pragma unroll
    for (int r = 0; r < 4; r++) {
      const float rn = vnorm[rowbase + i * 16 + g * 4 + r];
      float m = 3.0e38f;
      #pragma unroll
      for (int j = 0; j < 4; j++) {
        const float P = rn + cn[j] - 2.0f * acc[i][j][r];
        m = fminf(m, P);
        cmin[j] = fminf(cmin[j], P);
      }
      #pragma unroll
      for (int mm = 1; mm < 16; mm <<= 1)
        m = fminf(m, __shfl_xor(m, mm, 64));
      if (c == 0)
        atomicMin(&rowmin[rowbase + i * 16 + g * 4 + r], enc_f(m));
    }
  }
  #pragma unroll
  for (int j = 0; j < 4; j++) {
    float m = cmin[j];
    m = fminf(m, __shfl_xor(m, 16, 64));
    m = fminf(m, __shfl_xor(m, 32, 64));
    if (g == 0)
      atomicMin(&colmin[colbase + j * 16 + c], enc_f(m));
  }
}

// ---------------- fallback single-pass kernel (R2, used if ws too small) ----------------
#define LDP 72
__global__ __launch_bounds__(256, 2) void chamfer_fused(
    const float* __restrict__ video, const float* __restrict__ lang,
    unsigned* __restrict__ rowmin, unsigned* __restrict__ colmin) {
  __shared__ unsigned short Asm[BT][LDP];
  __shared__ unsigned short Bsm[BT][LDP];
  __shared__ float rn_s[BT];
  __shared__ float cn_s[BT];
  const int bid = blockIdx.x;
  const int b = bid >> 6, vt = (bid >> 2) & 15, lt = bid & 3;
  const float* Ag = video + ((size_t)b * NV + (size_t)vt * BT) * DK;
  const float* Bg = lang + ((size_t)b * NL + (size_t)lt * BT) * DK;
  const int t = threadIdx.x, lane = t & 63, w = t >> 6;
  const int wrow = (w >> 1) * 64, wcol = (w & 1) * 64;
  const int sg = t >> 4, sk = (t & 15) * 4;
  float rnA[8], rnB[8];
  #pragma unroll
  for (int i = 0; i < 8; i++) { rnA[i] = 0.f; rnB[i] = 0.f; }
  f32x4 acc[4][4];
  #pragma unroll
  for (int i = 0; i < 4; i++)
    #pragma unroll
    for (int j = 0; j < 4; j++) acc[i][j] = (f32x4){0.f, 0.f, 0.f, 0.f};
  for (int k0 = 0; k0 < DK; k0 += BK) {
    __syncthreads();
    #pragma unroll
    for (int i = 0; i < 8; i++) {
      const int r = sg + 16 * i;
      const float4 va = *(const float4*)(Ag + (size_t)r * DK + k0 + sk);
      const float4 vb = *(const float4*)(Bg + (size_t)r * DK + k0 + sk);
      rnA[i] += va.x * va.x + va.y * va.y + va.z * va.z + va.w * va.w;
      rnB[i] += vb.x * vb.x + vb.y * vb.y + vb.z * vb.z + vb.w * vb.w;
      uint2 pa, pb;
      pa.x = pack_bf2(va.x, va.y); pa.y = pack_bf2(va.z, va.w);
      pb.x = pack_bf2(vb.x, vb.y); pb.y = pack_bf2(vb.z, vb.w);
      *(uint2*)&Asm[r][sk] = pa;
      *(uint2*)&Bsm[r][sk] = pb;
    }
    __syncthreads();
    #pragma unroll
    for (int ks = 0; ks < 2; ks++) {
      const int kb = ks * 32 + (lane >> 4) * 8;
      bf16x8 af[4], bfr[4];
      #pragma unroll
      for (int i = 0; i < 4; i++) af[i] = *(const bf16x8*)&Asm[wrow + i * 16 + (lane & 15)][kb];
      #pragma unroll
      for (int j = 0; j < 4; j++) bfr[j] = *(const bf16x8*)&Bsm[wcol + j * 16 + (lane & 15)][kb];
      #pragma unroll
      for (int i = 0; i < 4; i++)
        #pragma unroll
        for (int j = 0; j < 4; j++)
          acc[i][j] = __builtin_amdgcn_mfma_f32_16x16x32_bf16(af[i], bfr[j], acc[i][j], 0, 0, 0);
    }
  }
  #pragma unroll
  for (int i = 0; i < 8; i++) {
    float a = rnA[i], bb = rnB[i];
    #pragma unroll
    for (int m = 1; m < 16; m <<= 1) { a += __shfl_xor(a, m, 64); bb += __shfl_xor(bb, m, 64); }
    rnA[i] = a; rnB[i] = bb;
  }
  if ((t & 15) == 0) {
    #pragma unroll
    for (int i = 0; i < 8; i++) { rn_s[sg + 16 * i] = rnA[i]; cn_s[sg + 16 * i] = rnB[i]; }
  }
  __syncthreads();
  const int g = lane >> 4, c = lane & 15;
  float cn[4];
  #pragma unroll
  for (int j = 0; j < 4; j++) cn[j] = cn_s[wcol + j * 16 + c];
  const size_t rowbase = (size_t)b * NV + (size_t)vt * BT + wrow;
  const size_t colbase = (size_t)b * NL + (size_t)lt * BT + wcol;
  float cmin[4];
  #pragma unroll
  for (int j = 0; j < 4; j++) cmin[j] = 3.0e38f;
  #pragma unroll
  for (int i = 0; i < 4; i++) {
    #pragma unroll
    for (int r = 0; r < 4; r++) {
      const float rn = rn_s[wrow + i * 16 + g * 4 + r];
      float m = 3.0e38f;
      #pragma unroll
      for (int j = 0; j < 4; j++) {
        const float P = rn + cn[j] - 2.0f * acc[i][j][r];
        m = fminf(m, P); cmin[j] = fminf(cmin[j], P);
      }
      #pragma unroll
      for (int mm = 1; mm < 16; mm <<= 1) m = fminf(m, __shfl_xor(m, mm, 64));
      if (c == 0) atomicMin(&rowmin[rowbase + i * 16 + g * 4 + r], enc_f(m));
    }
  }
  #pragma unroll
  for (int j = 0; j < 4; j++) {
    float m = cmin[j];
    m = fminf(m, __shfl_xor(m, 16, 64));
    m = fminf(m, __shfl_xor(m, 32, 64));
    if (g == 0) atomicMin(&colmin[colbase + j * 16 + c], enc_f(m));
  }
}

__global__ void chamfer_reduce(const unsigned* __restrict__ rowmin,
                               const unsigned* __restrict__ colmin,
                               float* __restrict__ out) {
  const int b = blockIdx.x;
  const int t = threadIdx.x;
  float s = 0.f;
  for (int i = t; i < NV; i += 256) s += dec_f(rowmin[(size_t)b * NV + i]) * (1.0f / NV);
  for (int i = t; i < NL; i += 256) s += dec_f(colmin[(size_t)b * NL + i]) * (1.0f / NL);
  #pragma unroll
  for (int m = 1; m < 64; m <<= 1) s += __shfl_xor(s, m, 64);
  __shared__ float ws[4];
  if ((t & 63) == 0) ws[t >> 6] = s;
  __syncthreads();
  if (t == 0) out[b] = ws[0] + ws[1] + ws[2] + ws[3];
}

extern "C" void kernel_launch(void* const* d_in, const int* in_sizes, int n_in,
                              void* d_out, int out_size, void* d_ws, size_t ws_size,
                              hipStream_t stream) {
  const float* video = (const float*)d_in[0];
  const float* lang  = (const float*)d_in[1];
  float* out = (float*)d_out;

  const size_t vb_elems = (size_t)NB * NV * DK;   // 67.1M bf16
  const size_t lb_elems = (size_t)NB * NL * DK;   // 16.8M bf16
  const size_t need = vb_elems * 2 + lb_elems * 2 +
                      (size_t)(NB * NV + NB * NL) * 4 * 2;  // bf16 bufs + norms + mins

  if (ws_size >= need) {
    unsigned short* Vb = (unsigned short*)d_ws;
    unsigned short* Lb = Vb + vb_elems;
    float* vnorm = (float*)(Lb + lb_elems);
    float* lnorm = vnorm + (size_t)NB * NV;
    unsigned* rowmin = (unsigned*)(lnorm + (size_t)NB * NL);
    unsigned* colmin = rowmin + (size_t)NB * NV;
    (void)hipMemsetAsync(rowmin, 0xFF, (size_t)(NB * NV + NB * NL) * sizeof(unsigned), stream);
    convert_norm<<<dim3((NB * NV + NB * NL) / 4), dim3(256), 0, stream>>>(
        video, lang, Vb, Lb, vnorm, lnorm);
    chamfer_gemm<<<dim3(NB * 16 * 4), dim3(256), 0, stream>>>(
        Vb, Lb, vnorm, lnorm, rowmin, colmin);
    chamfer_reduce<<<dim3(NB), dim3(256), 0, stream>>>(rowmin, colmin, out);
  } else {
    unsigned* rowmin = (unsigned*)d_ws;
    unsigned* colmin = rowmin + (size_t)NB * NV;
    (void)hipMemsetAsync(d_ws, 0xFF, (size_t)(NB * NV + NB * NL) * sizeof(unsigned), stream);
    chamfer_fused<<<dim3(NB * 16 * 4), dim3(256), 0, stream>>>(video, lang, rowmin, colmin);
    chamfer_reduce<<<dim3(NB), dim3(256), 0, stream>>>(rowmin, colmin, out);
  }
}

// Round 4
// 518.000 us; speedup vs baseline: 1.3768x; 1.0112x over previous
//
#include <hip/hip_runtime.h>
#include <hip/hip_bf16.h>
#include <stdint.h>

#define NB 64
#define NV 2048
#define NL 512
#define DK 512
#define BT 128
#define BK 64

typedef __attribute__((ext_vector_type(8))) short bf16x8;
typedef __attribute__((ext_vector_type(4))) float f32x4;

// order-preserving float -> uint map (for atomicMin); all-ones = +infinity sentinel
__device__ __forceinline__ unsigned enc_f(float f) {
  unsigned u = __float_as_uint(f);
  return (u & 0x80000000u) ? ~u : (u | 0x80000000u);
}
__device__ __forceinline__ float dec_f(unsigned u) {
  unsigned b = (u & 0x80000000u) ? (u ^ 0x80000000u) : ~u;
  return __uint_as_float(b);
}

// fp32 -> bf16 (RNE); inputs finite, no NaN path
__device__ __forceinline__ unsigned short f2bf(float f) {
  unsigned u = __float_as_uint(f);
  u += 0x7FFFu + ((u >> 16) & 1u);
  return (unsigned short)(u >> 16);
}
__device__ __forceinline__ unsigned pack_bf2(float lo, float hi) {
  return (unsigned)f2bf(lo) | ((unsigned)f2bf(hi) << 16);
}

// async global->LDS, 16 B per lane; LDS dest = wave-uniform base + lane*16
__device__ __forceinline__ void gload_lds16(const void* g, void* l) {
  __builtin_amdgcn_global_load_lds(
      (const __attribute__((address_space(1))) unsigned*)g,
      (__attribute__((address_space(3))) unsigned*)l, 16, 0, 0);
}

// ---------------- Pass 1: fp32 -> bf16 + exact fp32 row norms + min-sentinel init -------
// one wave per row of 512 floats; lane handles 8 consecutive elems -> one 16B store.
__global__ __launch_bounds__(256) void convert_norm(
    const float* __restrict__ video, const float* __restrict__ lang,
    unsigned short* __restrict__ Vb, unsigned short* __restrict__ Lb,
    float* __restrict__ vnorm, float* __restrict__ lnorm,
    unsigned* __restrict__ rowmin, unsigned* __restrict__ colmin) {
  const int t = threadIdx.x;
  const int lane = t & 63;
  const int row = blockIdx.x * 4 + (t >> 6);
  const int rows_v = NB * NV;

  const float* src;
  unsigned short* dst;
  float* nrm;
  unsigned* sent;
  size_t r;
  if (row < rows_v) { src = video; dst = Vb; nrm = vnorm; sent = rowmin; r = (size_t)row; }
  else              { src = lang;  dst = Lb;  nrm = lnorm; sent = colmin; r = (size_t)(row - rows_v); }

  const float4* p = (const float4*)(src + r * DK);
  const float4 a = p[lane * 2];
  const float4 b = p[lane * 2 + 1];

  float n = a.x * a.x + a.y * a.y + a.z * a.z + a.w * a.w
          + b.x * b.x + b.y * b.y + b.z * b.z + b.w * b.w;
  #pragma unroll
  for (int m = 1; m < 64; m <<= 1) n += __shfl_xor(n, m, 64);

  uint4 pk;
  pk.x = pack_bf2(a.x, a.y); pk.y = pack_bf2(a.z, a.w);
  pk.z = pack_bf2(b.x, b.y); pk.w = pack_bf2(b.z, b.w);
  ((uint4*)(dst + r * DK))[lane] = pk;
  if (lane == 0) {
    nrm[r] = n;
    sent[r] = 0xFFFFFFFFu;   // +inf sentinel for atomicMin
  }
}

// ---------------- Pass 2: bf16 GEMM + chamfer mins ----------------
// XCD-swizzled grid: xcd = bid&7 owns 8 contiguous batches -> A/B tile re-reads hit
// that XCD's L2 instead of crossing to L3.
// block 256 = 4 waves, each 64x64 out. LDS [128][64] bf16 unpadded with XOR chunk
// swizzle (slot = chunk ^ (row&7)) -> conflict-minimal ds_read_b128.
__global__ __launch_bounds__(256, 4) void chamfer_gemm(
    const unsigned short* __restrict__ Vb, const unsigned short* __restrict__ Lb,
    const float* __restrict__ vnorm, const float* __restrict__ lnorm,
    unsigned* __restrict__ rowmin, unsigned* __restrict__ colmin) {
  __shared__ unsigned short Asm[BT][BK];
  __shared__ unsigned short Bsm[BT][BK];

  const int bid0 = blockIdx.x;
  const int bid = (bid0 & 7) * 512 + (bid0 >> 3);   // XCD-contiguous logical id
  const int b  = bid >> 6;
  const int vt = (bid >> 2) & 15;
  const int lt = bid & 3;

  const unsigned short* Ag = Vb + ((size_t)b * NV + (size_t)vt * BT) * DK;
  const unsigned short* Bg = Lb + ((size_t)b * NL + (size_t)lt * BT) * DK;

  const int t = threadIdx.x;
  const int lane = t & 63;
  const int w = t >> 6;
  const int wrow = (w >> 1) * 64;
  const int wcol = (w & 1) * 64;

  // staging: each wave stages 32 rows of A and 32 rows of B (4 instrs each, 8 rows/instr)
  const int lr = lane >> 3;        // row within 8-row group
  const int lp = lane & 7;         // dest slot within row
  const int schunk = lp ^ lr;      // source chunk (XOR swizzle)

  f32x4 acc[4][4];
  #pragma unroll
  for (int i = 0; i < 4; i++)
    #pragma unroll
    for (int j = 0; j < 4; j++)
      acc[i][j] = (f32x4){0.f, 0.f, 0.f, 0.f};

  const int c16 = lane & 15;
  const int hi  = lane >> 4;       // 0..3
  const int sw  = c16 & 7;         // read-side swizzle key (row&7)

  for (int k0 = 0; k0 < DK; k0 += BK) {
    __syncthreads();               // all waves done reading previous tile
    #pragma unroll
    for (int s = 0; s < 4; s++) {
      const int row = w * 32 + s * 8 + lr;
      gload_lds16(Ag + (size_t)row * DK + k0 + schunk * 8, &Asm[w * 32 + s * 8][0]);
      gload_lds16(Bg + (size_t)row * DK + k0 + schunk * 8, &Bsm[w * 32 + s * 8][0]);
    }
    __syncthreads();               // vmcnt(0) drain -> tile visible
    #pragma unroll
    for (int ks = 0; ks < 2; ks++) {
      const int ck = ks * 4 + hi;  // logical 16B chunk index in row
      bf16x8 af[4], bfr[4];
      #pragma unroll
      for (int i = 0; i < 4; i++)
        af[i] = *(const bf16x8*)&Asm[wrow + i * 16 + c16][(ck ^ sw) * 8];
      #pragma unroll
      for (int j = 0; j < 4; j++)
        bfr[j] = *(const bf16x8*)&Bsm[wcol + j * 16 + c16][(ck ^ sw) * 8];
      #pragma unroll
      for (int i = 0; i < 4; i++)
        #pragma unroll
        for (int j = 0; j < 4; j++)
          acc[i][j] = __builtin_amdgcn_mfma_f32_16x16x32_bf16(af[i], bfr[j], acc[i][j], 0, 0, 0);
    }
  }

  // epilogue: P = rn + cn - 2*dot; C layout col=lane&15, row=(lane>>4)*4+reg
  const int g = hi;
  const int c = c16;
  const size_t rowbase = (size_t)b * NV + (size_t)vt * BT + wrow;
  const size_t colbase = (size_t)b * NL + (size_t)lt * BT + wcol;

  float cn[4];
  #pragma unroll
  for (int j = 0; j < 4; j++) cn[j] = lnorm[colbase + j * 16 + c];

  float cmin[4];
  #pragma unroll
  for (int j = 0; j < 4; j++) cmin[j] = 3.0e38f;

  #pragma unroll
  for (int i = 0; i < 4; i++) {
    #pragma unroll
    for (int r = 0; r < 4; r++) {
      const float rn = vnorm[rowbase + i * 16 + g * 4 + r];
      float m = 3.0e38f;
      #pragma unroll
      for (int j = 0; j < 4; j++) {
        const float P = rn + cn[j] - 2.0f * acc[i][j][r];
        m = fminf(m, P);
        cmin[j] = fminf(cmin[j], P);
      }
      #pragma unroll
      for (int mm = 1; mm < 16; mm <<= 1)
        m = fminf(m, __shfl_xor(m, mm, 64));
      if (c == 0)
        atomicMin(&rowmin[rowbase + i * 16 + g * 4 + r], enc_f(m));
    }
  }
  #pragma unroll
  for (int j = 0; j < 4; j++) {
    float m = cmin[j];
    m = fminf(m, __shfl_xor(m, 16, 64));
    m = fminf(m, __shfl_xor(m, 32, 64));
    if (g == 0)
      atomicMin(&colmin[colbase + j * 16 + c], enc_f(m));
  }
}

__global__ void chamfer_reduce(const unsigned* __restrict__ rowmin,
                               const unsigned* __restrict__ colmin,
                               float* __restrict__ out) {
  const int b = blockIdx.x;
  const int t = threadIdx.x;
  float s = 0.f;
  for (int i = t; i < NV; i += 256) s += dec_f(rowmin[(size_t)b * NV + i]) * (1.0f / NV);
  for (int i = t; i < NL; i += 256) s += dec_f(colmin[(size_t)b * NL + i]) * (1.0f / NL);
  #pragma unroll
  for (int m = 1; m < 64; m <<= 1) s += __shfl_xor(s, m, 64);
  __shared__ float ws[4];
  if ((t & 63) == 0) ws[t >> 6] = s;
  __syncthreads();
  if (t == 0) out[b] = ws[0] + ws[1] + ws[2] + ws[3];
}

extern "C" void kernel_launch(void* const* d_in, const int* in_sizes, int n_in,
                              void* d_out, int out_size, void* d_ws, size_t ws_size,
                              hipStream_t stream) {
  const float* video = (const float*)d_in[0];
  const float* lang  = (const float*)d_in[1];
  float* out = (float*)d_out;

  const size_t vb_elems = (size_t)NB * NV * DK;   // 67.1M bf16
  const size_t lb_elems = (size_t)NB * NL * DK;   // 16.8M bf16

  unsigned short* Vb = (unsigned short*)d_ws;
  unsigned short* Lb = Vb + vb_elems;
  float* vnorm = (float*)(Lb + lb_elems);
  float* lnorm = vnorm + (size_t)NB * NV;
  unsigned* rowmin = (unsigned*)(lnorm + (size_t)NB * NL);
  unsigned* colmin = rowmin + (size_t)NB * NV;

  convert_norm<<<dim3((NB * NV + NB * NL) / 4), dim3(256), 0, stream>>>(
      video, lang, Vb, Lb, vnorm, lnorm, rowmin, colmin);
  chamfer_gemm<<<dim3(NB * 16 * 4), dim3(256), 0, stream>>>(
      Vb, Lb, vnorm, lnorm, rowmin, colmin);
  chamfer_reduce<<<dim3(NB), dim3(256), 0, stream>>>(rowmin, colmin, out);
}